// Round 1
// 1557.660 us; speedup vs baseline: 1.6171x; 1.6171x over previous
//
#include <hip/hip_runtime.h>

#define N_ENT   250002
#define DD      128
#define T_STEPS 16
#define E_EDGES 300000
#define S_SEEDS 256
#define C_NUM   50000
#define BASE    200000          // user_id_max + 1
#define NB      245             // scan blocks per step (245*1024 = 250880 >= N_ENT)
#define N_PAD   (NB * 1024)     // padded per-step offs row
#define NBKT    245             // dst buckets per step (dst >> 10), 245*1024 = N_PAD
#define BSH     10
#define CAPB    1536            // bucket capacity (mean 1224, sigma ~35 -> 8.9 sigma)
#define EPB     2048            // edges per bucketA block

typedef __attribute__((ext_vector_type(8))) short short8;
typedef __attribute__((ext_vector_type(4))) float f32x4;

__device__ inline unsigned short f2bf(float f) {
    unsigned u = __float_as_uint(f);
    u += 0x7FFFu + ((u >> 16) & 1u);          // RNE
    return (unsigned short)(u >> 16);
}
__device__ inline float bf_lo(unsigned p) { return __uint_as_float(p << 16); }
__device__ inline float bf_hi(unsigned p) { return __uint_as_float(p & 0xffff0000u); }
__device__ inline unsigned pk2(float x, float y) {
    return (unsigned)f2bf(x) | ((unsigned)f2bf(y) << 16);
}

// ---------------- init: node_bf <- bf16(ent); zero gcount/rowsum/out ----------------
#define NODE_W (N_ENT * 64)          // 16,000,128 unsigned (2 bf16 each)
#define GC_W   (T_STEPS * NBKT)      // 3,920 bucket counters
__global__ __launch_bounds__(256) void init_kernel(
    const float2* __restrict__ ent2, unsigned* __restrict__ node_bf,
    int* __restrict__ gcount, float* __restrict__ rowsum, float* __restrict__ out)
{
    int gid = blockIdx.x * 256 + threadIdx.x;
    if (gid < NODE_W) {
        float2 v = ent2[gid];
        node_bf[gid] = pk2(v.x, v.y);
    } else if (gid < NODE_W + GC_W) {
        gcount[gid - NODE_W] = 0;
    } else if (gid < NODE_W + GC_W + T_STEPS * S_SEEDS) {
        rowsum[gid - NODE_W - GC_W] = 0.f;
    } else if (gid == NODE_W + GC_W + T_STEPS * S_SEEDS) {
        out[0] = 0.f;
    }
}

// ---------------- convert all_c to bf16 (from pristine ent) ----------------
__global__ __launch_bounds__(256) void conv_kernel(
    const float4* __restrict__ c4, ushort4* __restrict__ cb4)
{
    int gid = blockIdx.x * 256 + threadIdx.x;    // C_NUM*128/4 = 1,600,000
    float4 v = c4[gid];
    cb4[gid] = make_ushort4(f2bf(v.x), f2bf(v.y), f2bf(v.z), f2bf(v.w));
}

// ---------------- CSR build A: bucketize edges by dst>>10 (dense chunk writes) ----------------
// entry = (src | rel<<18) | (dst_low10 << 22)
__global__ __launch_bounds__(256) void bucketA(
    const int* __restrict__ esrc, const int* __restrict__ edst, const int* __restrict__ erel,
    int* __restrict__ gcount, unsigned* __restrict__ bkt)
{
    int t = blockIdx.y;
    int base = blockIdx.x * EPB;
    int tid = threadIdx.x;
    __shared__ int lcnt[NBKT];
    __shared__ int lbase[NBKT];
    for (int i = tid; i < NBKT; i += 256) lcnt[i] = 0;
    __syncthreads();
    int dl[8], sr[8], off[8], bk[8];
    #pragma unroll
    for (int i = 0; i < 8; ++i) {
        int e = base + i * 256 + tid;
        bk[i] = -1;
        if (e < E_EDGES) {
            int eb = t * E_EDGES + e;
            int dd = edst[eb];
            sr[i] = esrc[eb] | (erel[eb] << 18);
            dl[i] = dd & ((1 << BSH) - 1);
            bk[i] = dd >> BSH;
            off[i] = atomicAdd(&lcnt[bk[i]], 1);
        }
    }
    __syncthreads();
    for (int i = tid; i < NBKT; i += 256)
        lbase[i] = atomicAdd(&gcount[t * NBKT + i], lcnt[i]);
    __syncthreads();
    #pragma unroll
    for (int i = 0; i < 8; ++i) {
        if (bk[i] >= 0) {
            int pos = lbase[bk[i]] + off[i];
            if (pos < CAPB)
                bkt[((size_t)(t * NBKT + bk[i])) * CAPB + pos] =
                    (unsigned)sr[i] | ((unsigned)dl[i] << 22);
        }
    }
}

// ---------------- CSR build B1: per-bucket LDS histogram -> offs counts ----------------
__global__ __launch_bounds__(256) void histB(
    const int* __restrict__ gcount, const unsigned* __restrict__ bkt,
    int* __restrict__ offs)
{
    int b = blockIdx.x, t = blockIdx.y, tid = threadIdx.x;
    __shared__ int cnt[1024];
    for (int i = tid; i < 1024; i += 256) cnt[i] = 0;
    __syncthreads();
    int n = min(gcount[t * NBKT + b], CAPB);
    const unsigned* bp = bkt + ((size_t)(t * NBKT + b)) * CAPB;
    for (int i = tid; i < n; i += 256)
        atomicAdd(&cnt[bp[i] >> 22], 1);
    __syncthreads();
    int* op = offs + (size_t)t * N_PAD + (b << BSH);
    for (int i = tid; i < 1024; i += 256) op[i] = cnt[i];
}

// ---------------- CSR build 2a: per-block partial sums ----------------
__global__ __launch_bounds__(256) void scanA_kernel(
    const int* __restrict__ offs, int* __restrict__ partials)
{
    int t = blockIdx.y, b = blockIdx.x, tid = threadIdx.x;
    const int4 v = *(const int4*)(offs + (size_t)t * N_PAD + b * 1024 + tid * 4);
    int s = v.x + v.y + v.z + v.w;
    #pragma unroll
    for (int off = 32; off > 0; off >>= 1) s += __shfl_xor(s, off, 64);
    __shared__ int wsum[4];
    int lane = tid & 63, wv = tid >> 6;
    if (lane == 0) wsum[wv] = s;
    __syncthreads();
    if (tid == 0) partials[t * NB + b] = wsum[0] + wsum[1] + wsum[2] + wsum[3];
}

// ---------------- CSR build 2b: exclusive scan of partials per step ----------------
__global__ __launch_bounds__(256) void scanB_kernel(int* __restrict__ partials)
{
    __shared__ int sc[256];
    int t = blockIdx.x, tid = threadIdx.x;
    int v = (tid < NB) ? partials[t * NB + tid] : 0;
    sc[tid] = v;
    __syncthreads();
    for (int off = 1; off < 256; off <<= 1) {
        int y = (tid >= off) ? sc[tid - off] : 0;
        __syncthreads();
        sc[tid] += y;
        __syncthreads();
    }
    if (tid < NB) partials[t * NB + tid] = (tid > 0) ? sc[tid - 1] : 0;
}

// ---------------- CSR build 2c: block-local exclusive scan + block prefix ----------------
__global__ __launch_bounds__(256) void scanC_kernel(
    int* __restrict__ offs, const int* __restrict__ partials)
{
    int t = blockIdx.y, b = blockIdx.x, tid = threadIdx.x;
    int* base = offs + (size_t)t * N_PAD + b * 1024 + tid * 4;
    int4 v = *(const int4*)base;
    int s = v.x + v.y + v.z + v.w;
    int lane = tid & 63, wv = tid >> 6;
    int x = s;                               // inclusive wave scan
    #pragma unroll
    for (int off = 1; off < 64; off <<= 1) {
        int y = __shfl_up(x, off, 64);
        if (lane >= off) x += y;
    }
    __shared__ int wsum[4];
    if (lane == 63) wsum[wv] = x;
    __syncthreads();
    int prefix = partials[t * NB + b];
    for (int w = 0; w < 4; ++w) prefix += (w < wv) ? wsum[w] : 0;
    int excl = prefix + x - s;               // exclusive of this thread's 4 elems
    int4 o;
    o.x = excl; o.y = o.x + v.x; o.z = o.y + v.y; o.w = o.z + v.z;
    *(int4*)base = o;
}

// ---------------- CSR build B2: per-bucket scatter into L2-local CSR window ----------------
// offs stays START offsets; sortedp entries are packed src|rel<<18 (4 B)
__global__ __launch_bounds__(256) void scatB(
    const int* __restrict__ gcount, const unsigned* __restrict__ bkt,
    const int* __restrict__ offs, unsigned* __restrict__ sortedp)
{
    int b = blockIdx.x, t = blockIdx.y, tid = threadIdx.x;
    __shared__ int cur[1024];
    const int* op = offs + (size_t)t * N_PAD + (b << BSH);
    for (int i = tid; i < 1024; i += 256) cur[i] = op[i];
    __syncthreads();
    int n = min(gcount[t * NBKT + b], CAPB);
    const unsigned* bp = bkt + ((size_t)(t * NBKT + b)) * CAPB;
    unsigned* sp = sortedp + (size_t)t * E_EDGES;
    for (int i = tid; i < n; i += 256) {
        unsigned e = bp[i];
        int pos = atomicAdd(&cur[e >> 22], 1);
        sp[pos] = e & 0x3FFFFFu;
    }
}

// ---------------- per-step: fused mean-message + residual update (ping-pong) ----------------
__global__ __launch_bounds__(256) void gather_fused(
    const unsigned* __restrict__ node_old, unsigned* __restrict__ node_new,
    const float2* __restrict__ rel2, const int* __restrict__ offs,
    const unsigned* __restrict__ sortedp, int t)
{
    int n = blockIdx.x * 4 + (threadIdx.x >> 6);
    int lane = threadIdx.x & 63;
    if (n >= N_ENT) return;
    const int* op = offs + (size_t)t * N_PAD;
    int start = op[n];
    int end = op[n + 1];
    size_t idx = (size_t)n * 64 + lane;
    unsigned nb = node_old[idx];
    if (end == start) { node_new[idx] = nb; return; }
    const unsigned* sp = sortedp + (size_t)t * E_EDGES;
    float ax = 0.f, ay = 0.f;
    for (int p = start; p < end; ++p) {
        unsigned pr = sp[p];
        unsigned src = pr & 0x3FFFFu;
        unsigned rl = pr >> 18;
        unsigned sb = node_old[(size_t)src * 64 + lane];
        float2 rv = rel2[rl * 64 + lane];
        ax += bf_lo(sb) * rv.x;
        ay += bf_hi(sb) * rv.y;
    }
    float inv = 1.0f / (float)(end - start);
    node_new[idx] = pk2(bf_lo(nb) + ax * inv, bf_hi(nb) + ay * inv);
}

// ---------------- per-step: snapshot seed rows into gathered[tt][4-j] (fp32) ----------------
__global__ __launch_bounds__(256) void gather_seed(
    const unsigned* __restrict__ node_bf, const int* __restrict__ seeds,
    float2* __restrict__ gath2, int t)
{
    int gid = blockIdx.x * 256 + threadIdx.x;   // 5*256*64 = 81920 threads
    int j = gid >> 14;
    int tt = t + j;
    if (tt >= T_STEPS) return;
    int rem = gid & 16383;
    int s = rem >> 6;
    int lane = rem & 63;
    int w = 4 - j;
    int node = seeds[tt * S_SEEDS + s];
    unsigned nb = node_bf[(size_t)node * 64 + lane];
    gath2[((tt * 5 + w) * S_SEEDS + s) * 64 + lane] = make_float2(bf_lo(nb), bf_hi(nb));
}

// ---------------- 5-snapshot attention per (t,s): one wave each; writes u fp32 + bf16 ----------------
__global__ __launch_bounds__(64) void attn_kernel(
    const float2* __restrict__ q2, const float2* __restrict__ g2,
    const int* __restrict__ seeds, float2* __restrict__ u2, unsigned* __restrict__ ubf)
{
    int b = blockIdx.x;          // 4096 = T*S
    int t = b >> 8;
    int s = b & 255;
    int lane = threadIdx.x;
    int seed = seeds[t * S_SEEDS + s];
    float2 q = q2[seed * 64 + lane];
    float2 g[5];
    float att[5];
    #pragma unroll
    for (int w = 0; w < 5; ++w) {
        float2 gv = g2[((t * 5 + w) * S_SEEDS + s) * 64 + lane];
        g[w] = gv;
        float p = gv.x * q.x + gv.y * q.y;
        #pragma unroll
        for (int off = 32; off > 0; off >>= 1) p += __shfl_xor(p, off, 64);
        att[w] = (w >= 4 - t) ? p : -1e9f;   // invalid slots masked -> weight exactly 0
    }
    float m = -1e30f;
    #pragma unroll
    for (int w = 0; w < 5; ++w) m = fmaxf(m, att[w]);
    float den = 0.f;
    #pragma unroll
    for (int w = 0; w < 5; ++w) den += __expf(att[w] - m);
    float invd = 1.0f / den;
    float2 o = make_float2(0.f, 0.f);
    #pragma unroll
    for (int w = 0; w < 5; ++w) {
        float wt = __expf(att[w] - m) * invd;
        o.x += wt * g[w].x;
        o.y += wt * g[w].y;
    }
    int idx = (t * S_SEEDS + s) * 64 + lane;
    u2[idx] = o;
    ubf[idx] = pk2(o.x, o.y);
}

// ---------------- MFMA score GEMM + streaming sum(exp) ----------------
__global__ __launch_bounds__(256) void score_mfma(
    const unsigned short* __restrict__ ub, const unsigned short* __restrict__ cb,
    float* __restrict__ rowsum)
{
    int tid = threadIdx.x;
    int wv = tid >> 6, lane = tid & 63;
    int col16 = lane & 15, quad = lane >> 4;
    int rb = blockIdx.x;                 // 64 row-blocks of 64 rows
    int j = blockIdx.y * 4 + wv;         // wave slice 0..31

    short8 a[4][4];
    #pragma unroll
    for (int g = 0; g < 4; ++g) {
        const unsigned short* ap = ub + (size_t)(rb * 64 + g * 16 + col16) * DD + quad * 8;
        #pragma unroll
        for (int kk = 0; kk < 4; ++kk)
            a[g][kk] = *(const short8*)(ap + kk * 32);
    }

    float es[4][4];
    #pragma unroll
    for (int g = 0; g < 4; ++g)
        #pragma unroll
        for (int r = 0; r < 4; ++r) es[g][r] = 0.f;

    for (int c = j; c < 3125; c += 32) {
        const unsigned short* bp = cb + (size_t)(c * 16 + col16) * DD + quad * 8;
        short8 b0 = *(const short8*)(bp);
        short8 b1 = *(const short8*)(bp + 32);
        short8 b2 = *(const short8*)(bp + 64);
        short8 b3 = *(const short8*)(bp + 96);
        #pragma unroll
        for (int g = 0; g < 4; ++g) {
            f32x4 d = {0.f, 0.f, 0.f, 0.f};
            d = __builtin_amdgcn_mfma_f32_16x16x32_bf16(a[g][0], b0, d, 0, 0, 0);
            d = __builtin_amdgcn_mfma_f32_16x16x32_bf16(a[g][1], b1, d, 0, 0, 0);
            d = __builtin_amdgcn_mfma_f32_16x16x32_bf16(a[g][2], b2, d, 0, 0, 0);
            d = __builtin_amdgcn_mfma_f32_16x16x32_bf16(a[g][3], b3, d, 0, 0, 0);
            #pragma unroll
            for (int r = 0; r < 4; ++r) es[g][r] += __expf(d[r]);
        }
    }

    #pragma unroll
    for (int g = 0; g < 4; ++g) {
        #pragma unroll
        for (int r = 0; r < 4; ++r) {
            float v = es[g][r];
            v += __shfl_xor(v, 1, 64);
            v += __shfl_xor(v, 2, 64);
            v += __shfl_xor(v, 4, 64);
            v += __shfl_xor(v, 8, 64);
            if (col16 == 0)
                atomicAdd(&rowsum[rb * 64 + g * 16 + quad * 4 + r], v);
        }
    }
}

// ---------------- final: loss = sum(log(rowsum) - pos), pos in fp32 ----------------
__global__ __launch_bounds__(256) void final_kernel(
    const float2* __restrict__ u2, const float* __restrict__ ent,
    const int* __restrict__ cidx, const float* __restrict__ rowsum,
    float* __restrict__ out)
{
    int wv = threadIdx.x >> 6, lane = threadIdx.x & 63;
    int row = blockIdx.x * 4 + wv;       // grid 1024 -> 4096 rows
    int ci = cidx[row];
    const float2* tp = (const float2*)(ent + (size_t)(BASE + ci) * DD);
    float2 a = u2[row * 64 + lane];
    float2 t = tp[lane];
    float p = a.x * t.x + a.y * t.y;
    #pragma unroll
    for (int off = 32; off > 0; off >>= 1) p += __shfl_xor(p, off, 64);
    if (lane == 0) atomicAdd(out, logf(rowsum[row]) - p);
}

extern "C" void kernel_launch(void* const* d_in, const int* in_sizes, int n_in,
                              void* d_out, int out_size, void* d_ws, size_t ws_size,
                              hipStream_t stream)
{
    (void)in_sizes; (void)n_in; (void)out_size; (void)ws_size;
    const float* ent   = (const float*)d_in[0];
    const float* query = (const float*)d_in[1];
    const float* rel   = (const float*)d_in[2];
    const int* esrc    = (const int*)d_in[3];
    const int* edst    = (const int*)d_in[4];
    const int* erel    = (const int*)d_in[5];
    const int* seeds   = (const int*)d_in[6];
    const int* cidx    = (const int*)d_in[7];
    float* out = (float*)d_out;

    // ws layout: nodeA | nodeB | offs | partials | gcount | bkt | sortedp | gath | u | ubf | cb | rowsum
    char* ws = (char*)d_ws;
    size_t off = 0;
    unsigned* nodeA   = (unsigned*)(ws + off);       off += (size_t)N_ENT * DD * 2;            // 64.0 MB
    unsigned* nodeB   = (unsigned*)(ws + off);       off += (size_t)N_ENT * DD * 2;            // 64.0 MB
    int*      offs    = (int*)(ws + off);            off += (size_t)T_STEPS * N_PAD * 4;       // 16.1 MB
    int*      partials= (int*)(ws + off);            off += (size_t)T_STEPS * NB * 4;          // 15.7 KB
    int*      gcount  = (int*)(ws + off);            off += (size_t)T_STEPS * NBKT * 4;        // 15.7 KB
    unsigned* bkt     = (unsigned*)(ws + off);       off += (size_t)T_STEPS * NBKT * CAPB * 4; // 24.1 MB
    unsigned* sortedp = (unsigned*)(ws + off);       off += (size_t)T_STEPS * E_EDGES * 4;     // 19.2 MB
    float*    gath    = (float*)(ws + off);          off += (size_t)T_STEPS * 5 * S_SEEDS * DD * 4;
    float*    u       = (float*)(ws + off);          off += (size_t)T_STEPS * S_SEEDS * DD * 4;
    unsigned* ubf     = (unsigned*)(ws + off);       off += (size_t)T_STEPS * S_SEEDS * DD * 2;
    unsigned short* cb = (unsigned short*)(ws + off); off += (size_t)C_NUM * DD * 2;
    float*    rsum    = (float*)(ws + off);          off += (size_t)T_STEPS * S_SEEDS * 4;

    int init_items = NODE_W + GC_W + T_STEPS * S_SEEDS + 1;
    init_kernel<<<(init_items + 255) / 256, 256, 0, stream>>>(
        (const float2*)ent, nodeA, gcount, rsum, out);
    conv_kernel<<<C_NUM * DD / 4 / 256, 256, 0, stream>>>(
        (const float4*)(ent + (size_t)BASE * DD), (ushort4*)cb);

    dim3 bgrid((E_EDGES + EPB - 1) / EPB, T_STEPS);   // (147, 16)
    dim3 kgrid(NBKT, T_STEPS);                        // (245, 16)
    dim3 sgrid(NB, T_STEPS);
    bucketA<<<bgrid, 256, 0, stream>>>(esrc, edst, erel, gcount, bkt);
    histB<<<kgrid, 256, 0, stream>>>(gcount, bkt, offs);
    scanA_kernel<<<sgrid, 256, 0, stream>>>(offs, partials);
    scanB_kernel<<<T_STEPS, 256, 0, stream>>>(partials);
    scanC_kernel<<<sgrid, 256, 0, stream>>>(offs, partials);
    scatB<<<kgrid, 256, 0, stream>>>(gcount, bkt, offs, sortedp);

    int ngrid = (N_ENT + 3) / 4;
    unsigned* cur = nodeA;
    unsigned* nxt = nodeB;
    for (int t = 0; t < T_STEPS; ++t) {
        gather_fused<<<ngrid, 256, 0, stream>>>(
            cur, nxt, (const float2*)rel, offs, sortedp, t);
        gather_seed<<<5 * S_SEEDS * 64 / 256, 256, 0, stream>>>(
            nxt, seeds, (float2*)gath, t);
        unsigned* tmp = cur; cur = nxt; nxt = tmp;
    }
    attn_kernel<<<T_STEPS * S_SEEDS, 64, 0, stream>>>(
        (const float2*)query, (const float2*)gath, seeds, (float2*)u, (unsigned*)ubf);
    score_mfma<<<dim3(64, 8), 256, 0, stream>>>((const unsigned short*)ubf, cb, rsum);
    final_kernel<<<T_STEPS * S_SEEDS / 4, 256, 0, stream>>>(
        (const float2*)u, ent, cidx, rsum, out);
}

// Round 2
// 1510.360 us; speedup vs baseline: 1.6678x; 1.0313x over previous
//
#include <hip/hip_runtime.h>

#define N_ENT   250002
#define DD      128
#define T_STEPS 16
#define E_EDGES 300000
#define S_SEEDS 256
#define C_NUM   50000
#define BASE    200000          // user_id_max + 1
#define NB      245             // scan blocks per step (245*1024 = 250880 >= N_ENT)
#define N_PAD   (NB * 1024)     // padded per-step offs row
#define NBKT    245             // dst buckets per step (dst >> 10), 245*1024 = N_PAD
#define BSH     10
#define CAPB    1536            // bucket capacity (mean 1229, sigma ~35 -> 8.8 sigma)
#define EPB     2048            // edges per bucketA block
#define NGRID_F ((N_ENT + 3) / 4)        // 62501 node blocks in fused gather
#define SEED_BLKS (5 * S_SEEDS / 4)      // 320 seed-snapshot blocks

typedef __attribute__((ext_vector_type(8))) short short8;
typedef __attribute__((ext_vector_type(4))) float f32x4;

__device__ inline unsigned short f2bf(float f) {
    unsigned u = __float_as_uint(f);
    u += 0x7FFFu + ((u >> 16) & 1u);          // RNE
    return (unsigned short)(u >> 16);
}
__device__ inline float bf_lo(unsigned p) { return __uint_as_float(p << 16); }
__device__ inline float bf_hi(unsigned p) { return __uint_as_float(p & 0xffff0000u); }
__device__ inline unsigned pk2(float x, float y) {
    return (unsigned)f2bf(x) | ((unsigned)f2bf(y) << 16);
}

// ---------------- init: node_bf <- bf16(ent); zero gcount/rowsum/out ----------------
#define NODE_W (N_ENT * 64)          // 16,000,128 unsigned (2 bf16 each)
#define GC_W   (T_STEPS * NBKT)      // 3,920 bucket counters
__global__ __launch_bounds__(256) void init_kernel(
    const float2* __restrict__ ent2, unsigned* __restrict__ node_bf,
    int* __restrict__ gcount, float* __restrict__ rowsum, float* __restrict__ out)
{
    int gid = blockIdx.x * 256 + threadIdx.x;
    if (gid < NODE_W) {
        float2 v = ent2[gid];
        node_bf[gid] = pk2(v.x, v.y);
    } else if (gid < NODE_W + GC_W) {
        gcount[gid - NODE_W] = 0;
    } else if (gid < NODE_W + GC_W + T_STEPS * S_SEEDS) {
        rowsum[gid - NODE_W - GC_W] = 0.f;
    } else if (gid == NODE_W + GC_W + T_STEPS * S_SEEDS) {
        out[0] = 0.f;
    }
}

// ---------------- convert all_c to bf16 (from pristine ent) ----------------
__global__ __launch_bounds__(256) void conv_kernel(
    const float4* __restrict__ c4, ushort4* __restrict__ cb4)
{
    int gid = blockIdx.x * 256 + threadIdx.x;    // C_NUM*128/4 = 1,600,000
    float4 v = c4[gid];
    cb4[gid] = make_ushort4(f2bf(v.x), f2bf(v.y), f2bf(v.z), f2bf(v.w));
}

// ---------------- CSR build A: bucketize edges by dst>>10 (dense chunk writes) ----------------
// entry = (src | rel<<18) | (dst_low10 << 22)
__global__ __launch_bounds__(256) void bucketA(
    const int* __restrict__ esrc, const int* __restrict__ edst, const int* __restrict__ erel,
    int* __restrict__ gcount, unsigned* __restrict__ bkt)
{
    int t = blockIdx.y;
    int base = blockIdx.x * EPB;
    int tid = threadIdx.x;
    __shared__ int lcnt[NBKT];
    __shared__ int lbase[NBKT];
    for (int i = tid; i < NBKT; i += 256) lcnt[i] = 0;
    __syncthreads();
    int dl[8], sr[8], off[8], bk[8];
    #pragma unroll
    for (int i = 0; i < 8; ++i) {
        int e = base + i * 256 + tid;
        bk[i] = -1;
        if (e < E_EDGES) {
            int eb = t * E_EDGES + e;
            int dd = edst[eb];
            sr[i] = esrc[eb] | (erel[eb] << 18);
            dl[i] = dd & ((1 << BSH) - 1);
            bk[i] = dd >> BSH;
            off[i] = atomicAdd(&lcnt[bk[i]], 1);
        }
    }
    __syncthreads();
    for (int i = tid; i < NBKT; i += 256)
        lbase[i] = atomicAdd(&gcount[t * NBKT + i], lcnt[i]);
    __syncthreads();
    #pragma unroll
    for (int i = 0; i < 8; ++i) {
        if (bk[i] >= 0) {
            int pos = lbase[bk[i]] + off[i];
            if (pos < CAPB)
                bkt[((size_t)(t * NBKT + bk[i])) * CAPB + pos] =
                    (unsigned)sr[i] | ((unsigned)dl[i] << 22);
        }
    }
}

// ---------------- CSR build B1: per-bucket LDS histogram -> offs counts + block partial ----------------
// per-scan-block sum of counts == bucket count, so write partials here (scanA eliminated)
__global__ __launch_bounds__(256) void histB(
    const int* __restrict__ gcount, const unsigned* __restrict__ bkt,
    int* __restrict__ offs, int* __restrict__ partials)
{
    int b = blockIdx.x, t = blockIdx.y, tid = threadIdx.x;
    __shared__ int cnt[1024];
    for (int i = tid; i < 1024; i += 256) cnt[i] = 0;
    __syncthreads();
    int n = min(gcount[t * NBKT + b], CAPB);
    const unsigned* bp = bkt + ((size_t)(t * NBKT + b)) * CAPB;
    for (int i = tid; i < n; i += 256)
        atomicAdd(&cnt[bp[i] >> 22], 1);
    __syncthreads();
    int* op = offs + (size_t)t * N_PAD + (b << BSH);
    for (int i = tid; i < 1024; i += 256) op[i] = cnt[i];
    if (tid == 0) partials[t * NB + b] = n;
}

// ---------------- CSR build 2b: exclusive scan of partials per step ----------------
__global__ __launch_bounds__(256) void scanB_kernel(int* __restrict__ partials)
{
    __shared__ int sc[256];
    int t = blockIdx.x, tid = threadIdx.x;
    int v = (tid < NB) ? partials[t * NB + tid] : 0;
    sc[tid] = v;
    __syncthreads();
    for (int off = 1; off < 256; off <<= 1) {
        int y = (tid >= off) ? sc[tid - off] : 0;
        __syncthreads();
        sc[tid] += y;
        __syncthreads();
    }
    if (tid < NB) partials[t * NB + tid] = (tid > 0) ? sc[tid - 1] : 0;
}

// ---------------- CSR build 2c: block-local exclusive scan + block prefix ----------------
__global__ __launch_bounds__(256) void scanC_kernel(
    int* __restrict__ offs, const int* __restrict__ partials)
{
    int t = blockIdx.y, b = blockIdx.x, tid = threadIdx.x;
    int* base = offs + (size_t)t * N_PAD + b * 1024 + tid * 4;
    int4 v = *(const int4*)base;
    int s = v.x + v.y + v.z + v.w;
    int lane = tid & 63, wv = tid >> 6;
    int x = s;                               // inclusive wave scan
    #pragma unroll
    for (int off = 1; off < 64; off <<= 1) {
        int y = __shfl_up(x, off, 64);
        if (lane >= off) x += y;
    }
    __shared__ int wsum[4];
    if (lane == 63) wsum[wv] = x;
    __syncthreads();
    int prefix = partials[t * NB + b];
    for (int w = 0; w < 4; ++w) prefix += (w < wv) ? wsum[w] : 0;
    int excl = prefix + x - s;               // exclusive of this thread's 4 elems
    int4 o;
    o.x = excl; o.y = o.x + v.x; o.z = o.y + v.y; o.w = o.z + v.z;
    *(int4*)base = o;
}

// ---------------- CSR build B2: per-bucket scatter into L2-local CSR window ----------------
// offs stays START offsets; sortedp entries are packed src|rel<<18 (4 B)
__global__ __launch_bounds__(256) void scatB(
    const int* __restrict__ gcount, const unsigned* __restrict__ bkt,
    const int* __restrict__ offs, unsigned* __restrict__ sortedp)
{
    int b = blockIdx.x, t = blockIdx.y, tid = threadIdx.x;
    __shared__ int cur[1024];
    const int* op = offs + (size_t)t * N_PAD + (b << BSH);
    for (int i = tid; i < 1024; i += 256) cur[i] = op[i];
    __syncthreads();
    int n = min(gcount[t * NBKT + b], CAPB);
    const unsigned* bp = bkt + ((size_t)(t * NBKT + b)) * CAPB;
    unsigned* sp = sortedp + (size_t)t * E_EDGES;
    for (int i = tid; i < n; i += 256) {
        unsigned e = bp[i];
        int pos = atomicAdd(&cur[e >> 22], 1);
        sp[pos] = e & 0x3FFFFFu;
    }
}

// ---------------- per-step: fused mean-message + residual update (ping-pong) ----------------
// blocks [0, NGRID_F): update node_new.  blocks [NGRID_F, +SEED_BLKS): recompute the
// updated value of a seed node (bit-identical path) and write the fp32 snapshot to gath.
__global__ __launch_bounds__(256) void gather_fused(
    const unsigned* __restrict__ node_old, unsigned* __restrict__ node_new,
    const float2* __restrict__ rel2, const int* __restrict__ offs,
    const unsigned* __restrict__ sortedp, const int* __restrict__ seeds,
    float2* __restrict__ gath2, int t)
{
    int wv = threadIdx.x >> 6, lane = threadIdx.x & 63;
    int bx = blockIdx.x;
    int n, gslot = -1;
    if (bx < NGRID_F) {
        n = bx * 4 + wv;
        if (n >= N_ENT) return;
    } else {
        int g = (bx - NGRID_F) * 4 + wv;        // 0..1279
        int j = g >> 8;
        if (t + j >= T_STEPS) return;
        n = seeds[t * S_SEEDS + g];             // == seeds[(t+j)*256 + (g&255)]
        gslot = (((t + j) * 5 + (4 - j)) * S_SEEDS + (g & 255)) * 64 + lane;
    }
    const int* op = offs + (size_t)t * N_PAD;
    int start = op[n];
    int end = op[n + 1];
    size_t idx = (size_t)n * 64 + lane;
    unsigned nb = node_old[idx];
    float vx = bf_lo(nb), vy = bf_hi(nb);
    if (end > start) {
        const unsigned* sp = sortedp + (size_t)t * E_EDGES;
        float ax = 0.f, ay = 0.f;
        // software-pipelined: issue edge p+1's loads before consuming edge p
        int p = start;
        unsigned pr0 = sp[p];
        unsigned sb0 = node_old[(size_t)(pr0 & 0x3FFFFu) * 64 + lane];
        for (++p; p < end; ++p) {
            unsigned pr1 = sp[p];
            unsigned sb1 = node_old[(size_t)(pr1 & 0x3FFFFu) * 64 + lane];
            float2 rv = rel2[(pr0 >> 18) * 64 + lane];
            ax += bf_lo(sb0) * rv.x;
            ay += bf_hi(sb0) * rv.y;
            pr0 = pr1; sb0 = sb1;
        }
        float2 rv = rel2[(pr0 >> 18) * 64 + lane];
        ax += bf_lo(sb0) * rv.x;
        ay += bf_hi(sb0) * rv.y;
        float inv = 1.0f / (float)(end - start);
        vx += ax * inv;
        vy += ay * inv;
    }
    unsigned pkv = pk2(vx, vy);                 // same rounding on both paths
    if (gslot >= 0)
        gath2[gslot] = make_float2(bf_lo(pkv), bf_hi(pkv));
    else
        node_new[idx] = pkv;
}

// ---------------- 5-snapshot attention per (t,s): one wave each; writes u fp32 + bf16 ----------------
__global__ __launch_bounds__(64) void attn_kernel(
    const float2* __restrict__ q2, const float2* __restrict__ g2,
    const int* __restrict__ seeds, float2* __restrict__ u2, unsigned* __restrict__ ubf)
{
    int b = blockIdx.x;          // 4096 = T*S
    int t = b >> 8;
    int s = b & 255;
    int lane = threadIdx.x;
    int seed = seeds[t * S_SEEDS + s];
    float2 q = q2[seed * 64 + lane];
    float2 g[5];
    float att[5];
    #pragma unroll
    for (int w = 0; w < 5; ++w) {
        float2 gv = g2[((t * 5 + w) * S_SEEDS + s) * 64 + lane];
        g[w] = gv;
        float p = gv.x * q.x + gv.y * q.y;
        #pragma unroll
        for (int off = 32; off > 0; off >>= 1) p += __shfl_xor(p, off, 64);
        att[w] = (w >= 4 - t) ? p : -1e9f;   // invalid slots masked -> weight exactly 0
    }
    float m = -1e30f;
    #pragma unroll
    for (int w = 0; w < 5; ++w) m = fmaxf(m, att[w]);
    float den = 0.f;
    #pragma unroll
    for (int w = 0; w < 5; ++w) den += __expf(att[w] - m);
    float invd = 1.0f / den;
    float2 o = make_float2(0.f, 0.f);
    #pragma unroll
    for (int w = 0; w < 5; ++w) {
        float wt = __expf(att[w] - m) * invd;
        o.x += wt * g[w].x;
        o.y += wt * g[w].y;
    }
    int idx = (t * S_SEEDS + s) * 64 + lane;
    u2[idx] = o;
    ubf[idx] = pk2(o.x, o.y);
}

// ---------------- MFMA score GEMM + streaming sum(exp) ----------------
__global__ __launch_bounds__(256) void score_mfma(
    const unsigned short* __restrict__ ub, const unsigned short* __restrict__ cb,
    float* __restrict__ rowsum)
{
    int tid = threadIdx.x;
    int wv = tid >> 6, lane = tid & 63;
    int col16 = lane & 15, quad = lane >> 4;
    int rb = blockIdx.x;                 // 64 row-blocks of 64 rows
    int j = blockIdx.y * 4 + wv;         // wave slice 0..127

    short8 a[4][4];
    #pragma unroll
    for (int g = 0; g < 4; ++g) {
        const unsigned short* ap = ub + (size_t)(rb * 64 + g * 16 + col16) * DD + quad * 8;
        #pragma unroll
        for (int kk = 0; kk < 4; ++kk)
            a[g][kk] = *(const short8*)(ap + kk * 32);
    }

    float es[4][4];
    #pragma unroll
    for (int g = 0; g < 4; ++g)
        #pragma unroll
        for (int r = 0; r < 4; ++r) es[g][r] = 0.f;

    for (int c = j; c < 3125; c += 128) {
        const unsigned short* bp = cb + (size_t)(c * 16 + col16) * DD + quad * 8;
        short8 b0 = *(const short8*)(bp);
        short8 b1 = *(const short8*)(bp + 32);
        short8 b2 = *(const short8*)(bp + 64);
        short8 b3 = *(const short8*)(bp + 96);
        #pragma unroll
        for (int g = 0; g < 4; ++g) {
            f32x4 d = {0.f, 0.f, 0.f, 0.f};
            d = __builtin_amdgcn_mfma_f32_16x16x32_bf16(a[g][0], b0, d, 0, 0, 0);
            d = __builtin_amdgcn_mfma_f32_16x16x32_bf16(a[g][1], b1, d, 0, 0, 0);
            d = __builtin_amdgcn_mfma_f32_16x16x32_bf16(a[g][2], b2, d, 0, 0, 0);
            d = __builtin_amdgcn_mfma_f32_16x16x32_bf16(a[g][3], b3, d, 0, 0, 0);
            #pragma unroll
            for (int r = 0; r < 4; ++r) es[g][r] += __expf(d[r]);
        }
    }

    #pragma unroll
    for (int g = 0; g < 4; ++g) {
        #pragma unroll
        for (int r = 0; r < 4; ++r) {
            float v = es[g][r];
            v += __shfl_xor(v, 1, 64);
            v += __shfl_xor(v, 2, 64);
            v += __shfl_xor(v, 4, 64);
            v += __shfl_xor(v, 8, 64);
            if (col16 == 0)
                atomicAdd(&rowsum[rb * 64 + g * 16 + quad * 4 + r], v);
        }
    }
}

// ---------------- final: loss = sum(log(rowsum) - pos), pos in fp32 ----------------
__global__ __launch_bounds__(256) void final_kernel(
    const float2* __restrict__ u2, const float* __restrict__ ent,
    const int* __restrict__ cidx, const float* __restrict__ rowsum,
    float* __restrict__ out)
{
    int wv = threadIdx.x >> 6, lane = threadIdx.x & 63;
    int row = blockIdx.x * 4 + wv;       // grid 1024 -> 4096 rows
    int ci = cidx[row];
    const float2* tp = (const float2*)(ent + (size_t)(BASE + ci) * DD);
    float2 a = u2[row * 64 + lane];
    float2 t = tp[lane];
    float p = a.x * t.x + a.y * t.y;
    #pragma unroll
    for (int off = 32; off > 0; off >>= 1) p += __shfl_xor(p, off, 64);
    if (lane == 0) atomicAdd(out, logf(rowsum[row]) - p);
}

extern "C" void kernel_launch(void* const* d_in, const int* in_sizes, int n_in,
                              void* d_out, int out_size, void* d_ws, size_t ws_size,
                              hipStream_t stream)
{
    (void)in_sizes; (void)n_in; (void)out_size; (void)ws_size;
    const float* ent   = (const float*)d_in[0];
    const float* query = (const float*)d_in[1];
    const float* rel   = (const float*)d_in[2];
    const int* esrc    = (const int*)d_in[3];
    const int* edst    = (const int*)d_in[4];
    const int* erel    = (const int*)d_in[5];
    const int* seeds   = (const int*)d_in[6];
    const int* cidx    = (const int*)d_in[7];
    float* out = (float*)d_out;

    // ws layout: nodeA | nodeB | offs | partials | gcount | bkt | sortedp | gath | u | ubf | cb | rowsum
    char* ws = (char*)d_ws;
    size_t off = 0;
    unsigned* nodeA   = (unsigned*)(ws + off);       off += (size_t)N_ENT * DD * 2;            // 64.0 MB
    unsigned* nodeB   = (unsigned*)(ws + off);       off += (size_t)N_ENT * DD * 2;            // 64.0 MB
    int*      offs    = (int*)(ws + off);            off += (size_t)T_STEPS * N_PAD * 4;       // 16.1 MB
    int*      partials= (int*)(ws + off);            off += (size_t)T_STEPS * NB * 4;          // 15.7 KB
    int*      gcount  = (int*)(ws + off);            off += (size_t)T_STEPS * NBKT * 4;        // 15.7 KB
    unsigned* bkt     = (unsigned*)(ws + off);       off += (size_t)T_STEPS * NBKT * CAPB * 4; // 24.1 MB
    unsigned* sortedp = (unsigned*)(ws + off);       off += (size_t)T_STEPS * E_EDGES * 4;     // 19.2 MB
    float*    gath    = (float*)(ws + off);          off += (size_t)T_STEPS * 5 * S_SEEDS * DD * 4;
    float*    u       = (float*)(ws + off);          off += (size_t)T_STEPS * S_SEEDS * DD * 4;
    unsigned* ubf     = (unsigned*)(ws + off);       off += (size_t)T_STEPS * S_SEEDS * DD * 2;
    unsigned short* cb = (unsigned short*)(ws + off); off += (size_t)C_NUM * DD * 2;
    float*    rsum    = (float*)(ws + off);          off += (size_t)T_STEPS * S_SEEDS * 4;

    int init_items = NODE_W + GC_W + T_STEPS * S_SEEDS + 1;
    init_kernel<<<(init_items + 255) / 256, 256, 0, stream>>>(
        (const float2*)ent, nodeA, gcount, rsum, out);
    conv_kernel<<<C_NUM * DD / 4 / 256, 256, 0, stream>>>(
        (const float4*)(ent + (size_t)BASE * DD), (ushort4*)cb);

    dim3 bgrid((E_EDGES + EPB - 1) / EPB, T_STEPS);   // (147, 16)
    dim3 kgrid(NBKT, T_STEPS);                        // (245, 16)
    bucketA<<<bgrid, 256, 0, stream>>>(esrc, edst, erel, gcount, bkt);
    histB<<<kgrid, 256, 0, stream>>>(gcount, bkt, offs, partials);
    scanB_kernel<<<T_STEPS, 256, 0, stream>>>(partials);
    scanC_kernel<<<kgrid, 256, 0, stream>>>(offs, partials);
    scatB<<<kgrid, 256, 0, stream>>>(gcount, bkt, offs, sortedp);

    unsigned* cur = nodeA;
    unsigned* nxt = nodeB;
    for (int t = 0; t < T_STEPS; ++t) {
        gather_fused<<<NGRID_F + SEED_BLKS, 256, 0, stream>>>(
            cur, nxt, (const float2*)rel, offs, sortedp, seeds, (float2*)gath, t);
        unsigned* tmp = cur; cur = nxt; nxt = tmp;
    }
    attn_kernel<<<T_STEPS * S_SEEDS, 64, 0, stream>>>(
        (const float2*)query, (const float2*)gath, seeds, (float2*)u, (unsigned*)ubf);
    score_mfma<<<dim3(64, 32), 256, 0, stream>>>((const unsigned short*)ubf, cb, rsum);
    final_kernel<<<T_STEPS * S_SEEDS / 4, 256, 0, stream>>>(
        (const float2*)u, ent, cidx, rsum, out);
}

// Round 3
// 1085.873 us; speedup vs baseline: 2.3197x; 1.3909x over previous
//
#include <hip/hip_runtime.h>

#define N_ENT   250002
#define DD      128
#define T_STEPS 16
#define E_EDGES 300000
#define S_SEEDS 256
#define C_NUM   50000
#define BASE    200000          // user_id_max + 1
#define NB      245             // scan blocks per step (245*1024 = 250880 >= N_ENT)
#define N_PAD   (NB * 1024)     // padded per-step offs row
#define NBKT    245             // dst buckets per step (dst >> 10), 245*1024 = N_PAD
#define BSH     10
#define CAPB    1536            // bucket capacity (mean 1229, sigma ~35 -> 8.8 sigma)
#define EPB     2048            // edges per bucketA block
#define NGRID16 ((N_ENT + 15) / 16)      // 15626 node blocks (16 nodes/block, 4/wave)
#define SEED16  (5 * S_SEEDS / 16)       // 80 seed-snapshot blocks

typedef __attribute__((ext_vector_type(8))) short short8;
typedef __attribute__((ext_vector_type(4))) float f32x4;

__device__ inline unsigned short f2bf(float f) {
    unsigned u = __float_as_uint(f);
    u += 0x7FFFu + ((u >> 16) & 1u);          // RNE
    return (unsigned short)(u >> 16);
}
__device__ inline float bf_lo(unsigned p) { return __uint_as_float(p << 16); }
__device__ inline float bf_hi(unsigned p) { return __uint_as_float(p & 0xffff0000u); }
__device__ inline unsigned pk2(float x, float y) {
    return (unsigned)f2bf(x) | ((unsigned)f2bf(y) << 16);
}

// ---------------- init: node_bf <- bf16(ent); zero gcount/rowsum/out ----------------
#define NODE_W (N_ENT * 64)          // 16,000,128 unsigned (2 bf16 each)
#define GC_W   (T_STEPS * NBKT)      // 3,920 bucket counters
__global__ __launch_bounds__(256) void init_kernel(
    const float2* __restrict__ ent2, unsigned* __restrict__ node_bf,
    int* __restrict__ gcount, float* __restrict__ rowsum, float* __restrict__ out)
{
    int gid = blockIdx.x * 256 + threadIdx.x;
    if (gid < NODE_W) {
        float2 v = ent2[gid];
        node_bf[gid] = pk2(v.x, v.y);
    } else if (gid < NODE_W + GC_W) {
        gcount[gid - NODE_W] = 0;
    } else if (gid < NODE_W + GC_W + T_STEPS * S_SEEDS) {
        rowsum[gid - NODE_W - GC_W] = 0.f;
    } else if (gid == NODE_W + GC_W + T_STEPS * S_SEEDS) {
        out[0] = 0.f;
    }
}

// ---------------- convert all_c to bf16 (from pristine ent) ----------------
__global__ __launch_bounds__(256) void conv_kernel(
    const float4* __restrict__ c4, ushort4* __restrict__ cb4)
{
    int gid = blockIdx.x * 256 + threadIdx.x;    // C_NUM*128/4 = 1,600,000
    float4 v = c4[gid];
    cb4[gid] = make_ushort4(f2bf(v.x), f2bf(v.y), f2bf(v.z), f2bf(v.w));
}

// ---------------- CSR build A: bucketize edges by dst>>10 (dense chunk writes) ----------------
// entry = (src | rel<<18) | (dst_low10 << 22)
__global__ __launch_bounds__(256) void bucketA(
    const int* __restrict__ esrc, const int* __restrict__ edst, const int* __restrict__ erel,
    int* __restrict__ gcount, unsigned* __restrict__ bkt)
{
    int t = blockIdx.y;
    int base = blockIdx.x * EPB;
    int tid = threadIdx.x;
    __shared__ int lcnt[NBKT];
    __shared__ int lbase[NBKT];
    for (int i = tid; i < NBKT; i += 256) lcnt[i] = 0;
    __syncthreads();
    int dl[8], sr[8], off[8], bk[8];
    #pragma unroll
    for (int i = 0; i < 8; ++i) {
        int e = base + i * 256 + tid;
        bk[i] = -1;
        if (e < E_EDGES) {
            int eb = t * E_EDGES + e;
            int dd = edst[eb];
            sr[i] = esrc[eb] | (erel[eb] << 18);
            dl[i] = dd & ((1 << BSH) - 1);
            bk[i] = dd >> BSH;
            off[i] = atomicAdd(&lcnt[bk[i]], 1);
        }
    }
    __syncthreads();
    for (int i = tid; i < NBKT; i += 256)
        lbase[i] = atomicAdd(&gcount[t * NBKT + i], lcnt[i]);
    __syncthreads();
    #pragma unroll
    for (int i = 0; i < 8; ++i) {
        if (bk[i] >= 0) {
            int pos = lbase[bk[i]] + off[i];
            if (pos < CAPB)
                bkt[((size_t)(t * NBKT + bk[i])) * CAPB + pos] =
                    (unsigned)sr[i] | ((unsigned)dl[i] << 22);
        }
    }
}

// ---------------- CSR build B1: per-bucket LDS histogram -> offs counts + block partial ----------------
__global__ __launch_bounds__(256) void histB(
    const int* __restrict__ gcount, const unsigned* __restrict__ bkt,
    int* __restrict__ offs, int* __restrict__ partials)
{
    int b = blockIdx.x, t = blockIdx.y, tid = threadIdx.x;
    __shared__ int cnt[1024];
    for (int i = tid; i < 1024; i += 256) cnt[i] = 0;
    __syncthreads();
    int n = min(gcount[t * NBKT + b], CAPB);
    const unsigned* bp = bkt + ((size_t)(t * NBKT + b)) * CAPB;
    for (int i = tid; i < n; i += 256)
        atomicAdd(&cnt[bp[i] >> 22], 1);
    __syncthreads();
    int* op = offs + (size_t)t * N_PAD + (b << BSH);
    for (int i = tid; i < 1024; i += 256) op[i] = cnt[i];
    if (tid == 0) partials[t * NB + b] = n;
}

// ---------------- CSR build 2b: exclusive scan of partials per step ----------------
__global__ __launch_bounds__(256) void scanB_kernel(int* __restrict__ partials)
{
    __shared__ int sc[256];
    int t = blockIdx.x, tid = threadIdx.x;
    int v = (tid < NB) ? partials[t * NB + tid] : 0;
    sc[tid] = v;
    __syncthreads();
    for (int off = 1; off < 256; off <<= 1) {
        int y = (tid >= off) ? sc[tid - off] : 0;
        __syncthreads();
        sc[tid] += y;
        __syncthreads();
    }
    if (tid < NB) partials[t * NB + tid] = (tid > 0) ? sc[tid - 1] : 0;
}

// ---------------- CSR build 2c: block-local exclusive scan + block prefix ----------------
__global__ __launch_bounds__(256) void scanC_kernel(
    int* __restrict__ offs, const int* __restrict__ partials)
{
    int t = blockIdx.y, b = blockIdx.x, tid = threadIdx.x;
    int* base = offs + (size_t)t * N_PAD + b * 1024 + tid * 4;
    int4 v = *(const int4*)base;
    int s = v.x + v.y + v.z + v.w;
    int lane = tid & 63, wv = tid >> 6;
    int x = s;                               // inclusive wave scan
    #pragma unroll
    for (int off = 1; off < 64; off <<= 1) {
        int y = __shfl_up(x, off, 64);
        if (lane >= off) x += y;
    }
    __shared__ int wsum[4];
    if (lane == 63) wsum[wv] = x;
    __syncthreads();
    int prefix = partials[t * NB + b];
    for (int w = 0; w < 4; ++w) prefix += (w < wv) ? wsum[w] : 0;
    int excl = prefix + x - s;               // exclusive of this thread's 4 elems
    int4 o;
    o.x = excl; o.y = o.x + v.x; o.z = o.y + v.y; o.w = o.z + v.z;
    *(int4*)base = o;
}

// ---------------- CSR build B2: per-bucket scatter into L2-local CSR window ----------------
__global__ __launch_bounds__(256) void scatB(
    const int* __restrict__ gcount, const unsigned* __restrict__ bkt,
    const int* __restrict__ offs, unsigned* __restrict__ sortedp)
{
    int b = blockIdx.x, t = blockIdx.y, tid = threadIdx.x;
    __shared__ int cur[1024];
    const int* op = offs + (size_t)t * N_PAD + (b << BSH);
    for (int i = tid; i < 1024; i += 256) cur[i] = op[i];
    __syncthreads();
    int n = min(gcount[t * NBKT + b], CAPB);
    const unsigned* bp = bkt + ((size_t)(t * NBKT + b)) * CAPB;
    unsigned* sp = sortedp + (size_t)t * E_EDGES;
    for (int i = tid; i < n; i += 256) {
        unsigned e = bp[i];
        int pos = atomicAdd(&cur[e >> 22], 1);
        sp[pos] = e & 0x3FFFFFu;
    }
}

// ---------------- per-step: fused mean-message + residual update (ping-pong) ----------------
// 4 nodes per wave (16 lanes each, uint4 = 16B/lane) -> 4 independent memory chains/wave.
// blocks [0, NGRID16): update node_new.  blocks [NGRID16, +SEED16): recompute seed nodes
// (bit-identical path) and write fp32 snapshots to gath.
__global__ __launch_bounds__(256) void gather_fused(
    const unsigned* __restrict__ node_old, unsigned* __restrict__ node_new,
    const float2* __restrict__ rel2, const int* __restrict__ offs,
    const unsigned* __restrict__ sortedp, const int* __restrict__ seeds,
    float2* __restrict__ gath2, int t)
{
    int wv = threadIdx.x >> 6;
    int lane = threadIdx.x & 63;
    int grp = lane >> 4;          // 4 nodes per wave
    int l16 = lane & 15;          // 16 lanes per node, 16 B each
    int bx = blockIdx.x;
    int n = 0, gslot = -1;
    bool active;
    if (bx < NGRID16) {
        n = bx * 16 + wv * 4 + grp;
        active = (n < N_ENT);
    } else {
        int g = (bx - NGRID16) * 16 + wv * 4 + grp;   // 0..1279
        int j = g >> 8;
        active = (t + j < T_STEPS);
        if (active) {
            n = seeds[t * S_SEEDS + g];               // == seeds[(t+j)*256 + (g&255)]
            gslot = (((t + j) * 5 + (4 - j)) * S_SEEDS + (g & 255)) * 64 + l16 * 4;
        }
    }
    if (active) {
        const int* op = offs + (size_t)t * N_PAD;
        int start = op[n];
        int end = op[n + 1];
        uint4 nb = *((const uint4*)(node_old + (size_t)n * 64) + l16);
        float vx0 = bf_lo(nb.x), vy0 = bf_hi(nb.x);
        float vx1 = bf_lo(nb.y), vy1 = bf_hi(nb.y);
        float vx2 = bf_lo(nb.z), vy2 = bf_hi(nb.z);
        float vx3 = bf_lo(nb.w), vy3 = bf_hi(nb.w);
        if (end > start) {
            const unsigned* sp = sortedp + (size_t)t * E_EDGES;
            float ax0=0.f,ay0=0.f,ax1=0.f,ay1=0.f,ax2=0.f,ay2=0.f,ax3=0.f,ay3=0.f;
            for (int p = start; p < end; ++p) {
                unsigned pr = sp[p];
                uint4 sb = *((const uint4*)(node_old + (size_t)(pr & 0x3FFFFu) * 64) + l16);
                const float* rp = (const float*)(rel2 + (pr >> 18) * 64) + l16 * 8;
                float4 r01 = *(const float4*)rp;
                float4 r23 = *(const float4*)(rp + 4);
                ax0 += bf_lo(sb.x) * r01.x; ay0 += bf_hi(sb.x) * r01.y;
                ax1 += bf_lo(sb.y) * r01.z; ay1 += bf_hi(sb.y) * r01.w;
                ax2 += bf_lo(sb.z) * r23.x; ay2 += bf_hi(sb.z) * r23.y;
                ax3 += bf_lo(sb.w) * r23.z; ay3 += bf_hi(sb.w) * r23.w;
            }
            float inv = 1.0f / (float)(end - start);
            vx0 += ax0 * inv; vy0 += ay0 * inv;
            vx1 += ax1 * inv; vy1 += ay1 * inv;
            vx2 += ax2 * inv; vy2 += ay2 * inv;
            vx3 += ax3 * inv; vy3 += ay3 * inv;
        }
        uint4 o;
        o.x = pk2(vx0, vy0); o.y = pk2(vx1, vy1);
        o.z = pk2(vx2, vy2); o.w = pk2(vx3, vy3);
        if (gslot >= 0) {
            gath2[gslot + 0] = make_float2(bf_lo(o.x), bf_hi(o.x));
            gath2[gslot + 1] = make_float2(bf_lo(o.y), bf_hi(o.y));
            gath2[gslot + 2] = make_float2(bf_lo(o.z), bf_hi(o.z));
            gath2[gslot + 3] = make_float2(bf_lo(o.w), bf_hi(o.w));
        } else {
            *((uint4*)(node_new + (size_t)n * 64) + l16) = o;
        }
    }
}

// ---------------- 5-snapshot attention per (t,s): one wave each; writes u fp32 + bf16 ----------------
__global__ __launch_bounds__(64) void attn_kernel(
    const float2* __restrict__ q2, const float2* __restrict__ g2,
    const int* __restrict__ seeds, float2* __restrict__ u2, unsigned* __restrict__ ubf)
{
    int b = blockIdx.x;          // 4096 = T*S
    int t = b >> 8;
    int s = b & 255;
    int lane = threadIdx.x;
    int seed = seeds[t * S_SEEDS + s];
    float2 q = q2[seed * 64 + lane];
    float2 g[5];
    float att[5];
    #pragma unroll
    for (int w = 0; w < 5; ++w) {
        float2 gv = g2[((t * 5 + w) * S_SEEDS + s) * 64 + lane];
        g[w] = gv;
        float p = gv.x * q.x + gv.y * q.y;
        #pragma unroll
        for (int off = 32; off > 0; off >>= 1) p += __shfl_xor(p, off, 64);
        att[w] = (w >= 4 - t) ? p : -1e9f;   // invalid slots masked -> weight exactly 0
    }
    float m = -1e30f;
    #pragma unroll
    for (int w = 0; w < 5; ++w) m = fmaxf(m, att[w]);
    float den = 0.f;
    #pragma unroll
    for (int w = 0; w < 5; ++w) den += __expf(att[w] - m);
    float invd = 1.0f / den;
    float2 o = make_float2(0.f, 0.f);
    #pragma unroll
    for (int w = 0; w < 5; ++w) {
        float wt = __expf(att[w] - m) * invd;
        o.x += wt * g[w].x;
        o.y += wt * g[w].y;
    }
    int idx = (t * S_SEEDS + s) * 64 + lane;
    u2[idx] = o;
    ubf[idx] = pk2(o.x, o.y);
}

// ---------------- MFMA score GEMM + streaming sum(exp), depth-3 column prefetch ----------------
#define LOADC(B, cc) do { if ((cc) < 3125) {                                         \
    const unsigned short* bp_ = cb + (size_t)((cc) * 16 + col16) * DD + quad * 8;    \
    B[0] = *(const short8*)(bp_);      B[1] = *(const short8*)(bp_ + 32);            \
    B[2] = *(const short8*)(bp_ + 64); B[3] = *(const short8*)(bp_ + 96); } } while (0)

#define COMPUTE(B) do {                                                              \
    _Pragma("unroll")                                                                \
    for (int g = 0; g < 4; ++g) {                                                    \
        f32x4 d = {0.f, 0.f, 0.f, 0.f};                                              \
        d = __builtin_amdgcn_mfma_f32_16x16x32_bf16(a[g][0], B[0], d, 0, 0, 0);      \
        d = __builtin_amdgcn_mfma_f32_16x16x32_bf16(a[g][1], B[1], d, 0, 0, 0);      \
        d = __builtin_amdgcn_mfma_f32_16x16x32_bf16(a[g][2], B[2], d, 0, 0, 0);      \
        d = __builtin_amdgcn_mfma_f32_16x16x32_bf16(a[g][3], B[3], d, 0, 0, 0);      \
        _Pragma("unroll")                                                            \
        for (int r = 0; r < 4; ++r) es[g][r] += __expf(d[r]);                        \
    } } while (0)

__global__ __launch_bounds__(256) void score_mfma(
    const unsigned short* __restrict__ ub, const unsigned short* __restrict__ cb,
    float* __restrict__ rowsum)
{
    int tid = threadIdx.x;
    int wv = tid >> 6, lane = tid & 63;
    int col16 = lane & 15, quad = lane >> 4;
    int rb = blockIdx.x;                 // 64 row-blocks of 64 rows
    int j = blockIdx.y * 4 + wv;         // wave slice 0..63, column stride 64

    short8 a[4][4];
    #pragma unroll
    for (int g = 0; g < 4; ++g) {
        const unsigned short* ap = ub + (size_t)(rb * 64 + g * 16 + col16) * DD + quad * 8;
        #pragma unroll
        for (int kk = 0; kk < 4; ++kk)
            a[g][kk] = *(const short8*)(ap + kk * 32);
    }

    float es[4][4];
    #pragma unroll
    for (int g = 0; g < 4; ++g)
        #pragma unroll
        for (int r = 0; r < 4; ++r) es[g][r] = 0.f;

    short8 B0[4], B1[4], B2[4];
    LOADC(B0, j); LOADC(B1, j + 64); LOADC(B2, j + 128);
    for (int c = j; c < 3125; c += 192) {
        COMPUTE(B0); LOADC(B0, c + 192);
        if (c + 64 < 3125) { COMPUTE(B1); LOADC(B1, c + 256); }
        if (c + 128 < 3125) { COMPUTE(B2); LOADC(B2, c + 320); }
    }

    #pragma unroll
    for (int g = 0; g < 4; ++g) {
        #pragma unroll
        for (int r = 0; r < 4; ++r) {
            float v = es[g][r];
            v += __shfl_xor(v, 1, 64);
            v += __shfl_xor(v, 2, 64);
            v += __shfl_xor(v, 4, 64);
            v += __shfl_xor(v, 8, 64);
            if (col16 == 0)
                atomicAdd(&rowsum[rb * 64 + g * 16 + quad * 4 + r], v);
        }
    }
}

// ---------------- final: loss = sum(log(rowsum) - pos), pos in fp32 ----------------
__global__ __launch_bounds__(256) void final_kernel(
    const float2* __restrict__ u2, const float* __restrict__ ent,
    const int* __restrict__ cidx, const float* __restrict__ rowsum,
    float* __restrict__ out)
{
    int wv = threadIdx.x >> 6, lane = threadIdx.x & 63;
    int row = blockIdx.x * 4 + wv;       // grid 1024 -> 4096 rows
    int ci = cidx[row];
    const float2* tp = (const float2*)(ent + (size_t)(BASE + ci) * DD);
    float2 a = u2[row * 64 + lane];
    float2 t = tp[lane];
    float p = a.x * t.x + a.y * t.y;
    #pragma unroll
    for (int off = 32; off > 0; off >>= 1) p += __shfl_xor(p, off, 64);
    if (lane == 0) atomicAdd(out, logf(rowsum[row]) - p);
}

extern "C" void kernel_launch(void* const* d_in, const int* in_sizes, int n_in,
                              void* d_out, int out_size, void* d_ws, size_t ws_size,
                              hipStream_t stream)
{
    (void)in_sizes; (void)n_in; (void)out_size; (void)ws_size;
    const float* ent   = (const float*)d_in[0];
    const float* query = (const float*)d_in[1];
    const float* rel   = (const float*)d_in[2];
    const int* esrc    = (const int*)d_in[3];
    const int* edst    = (const int*)d_in[4];
    const int* erel    = (const int*)d_in[5];
    const int* seeds   = (const int*)d_in[6];
    const int* cidx    = (const int*)d_in[7];
    float* out = (float*)d_out;

    // ws layout: nodeA | nodeB | offs | partials | gcount | bkt | sortedp | gath | u | ubf | cb | rowsum
    char* ws = (char*)d_ws;
    size_t off = 0;
    unsigned* nodeA   = (unsigned*)(ws + off);       off += (size_t)N_ENT * DD * 2;            // 64.0 MB
    unsigned* nodeB   = (unsigned*)(ws + off);       off += (size_t)N_ENT * DD * 2;            // 64.0 MB
    int*      offs    = (int*)(ws + off);            off += (size_t)T_STEPS * N_PAD * 4;       // 16.1 MB
    int*      partials= (int*)(ws + off);            off += (size_t)T_STEPS * NB * 4;          // 15.7 KB
    int*      gcount  = (int*)(ws + off);            off += (size_t)T_STEPS * NBKT * 4;        // 15.7 KB
    unsigned* bkt     = (unsigned*)(ws + off);       off += (size_t)T_STEPS * NBKT * CAPB * 4; // 24.1 MB
    unsigned* sortedp = (unsigned*)(ws + off);       off += (size_t)T_STEPS * E_EDGES * 4;     // 19.2 MB
    float*    gath    = (float*)(ws + off);          off += (size_t)T_STEPS * 5 * S_SEEDS * DD * 4;
    float*    u       = (float*)(ws + off);          off += (size_t)T_STEPS * S_SEEDS * DD * 4;
    unsigned* ubf     = (unsigned*)(ws + off);       off += (size_t)T_STEPS * S_SEEDS * DD * 2;
    unsigned short* cb = (unsigned short*)(ws + off); off += (size_t)C_NUM * DD * 2;
    float*    rsum    = (float*)(ws + off);          off += (size_t)T_STEPS * S_SEEDS * 4;

    int init_items = NODE_W + GC_W + T_STEPS * S_SEEDS + 1;
    init_kernel<<<(init_items + 255) / 256, 256, 0, stream>>>(
        (const float2*)ent, nodeA, gcount, rsum, out);
    conv_kernel<<<C_NUM * DD / 4 / 256, 256, 0, stream>>>(
        (const float4*)(ent + (size_t)BASE * DD), (ushort4*)cb);

    dim3 bgrid((E_EDGES + EPB - 1) / EPB, T_STEPS);   // (147, 16)
    dim3 kgrid(NBKT, T_STEPS);                        // (245, 16)
    bucketA<<<bgrid, 256, 0, stream>>>(esrc, edst, erel, gcount, bkt);
    histB<<<kgrid, 256, 0, stream>>>(gcount, bkt, offs, partials);
    scanB_kernel<<<T_STEPS, 256, 0, stream>>>(partials);
    scanC_kernel<<<kgrid, 256, 0, stream>>>(offs, partials);
    scatB<<<kgrid, 256, 0, stream>>>(gcount, bkt, offs, sortedp);

    unsigned* cur = nodeA;
    unsigned* nxt = nodeB;
    for (int t = 0; t < T_STEPS; ++t) {
        gather_fused<<<NGRID16 + SEED16, 256, 0, stream>>>(
            cur, nxt, (const float2*)rel, offs, sortedp, seeds, (float2*)gath, t);
        unsigned* tmp = cur; cur = nxt; nxt = tmp;
    }
    attn_kernel<<<T_STEPS * S_SEEDS, 64, 0, stream>>>(
        (const float2*)query, (const float2*)gath, seeds, (float2*)u, (unsigned*)ubf);
    score_mfma<<<dim3(64, 16), 256, 0, stream>>>((const unsigned short*)ubf, cb, rsum);
    final_kernel<<<T_STEPS * S_SEEDS / 4, 256, 0, stream>>>(
        (const float2*)u, ent, cidx, rsum, out);
}